// Round 2
// baseline (123.027 us; speedup 1.0000x reference)
//
#include <hip/hip_runtime.h>
#include <math.h>

#define POOLED 7
#define SCALE 0.0625f
#define C_ 256
#define H_ 56
#define W_ 56
#define S_ (H_ * W_)   // 3136

// ---------- Kernel 1: NCHW -> NHWC transpose (per batch: (C,S) -> (S,C)) ----------
__global__ __launch_bounds__(256) void transpose_kernel(
    const float* __restrict__ feat, float* __restrict__ t)
{
    __shared__ float tile[64][65];
    int b  = blockIdx.z;
    int sbase = blockIdx.x * 64;   // 49 tiles over S=3136
    int cbase = blockIdx.y * 64;   // 4 tiles over C=256
    int tx = threadIdx.x & 63;
    int ty = threadIdx.x >> 6;     // 0..3

    const float* src = feat + ((size_t)b * C_) * S_;
    float* dst = t + ((size_t)b * S_) * C_;

    #pragma unroll
    for (int k = 0; k < 16; ++k) {
        int cl = ty * 16 + k;
        tile[cl][tx] = src[(size_t)(cbase + cl) * S_ + sbase + tx];
    }
    __syncthreads();
    #pragma unroll
    for (int k = 0; k < 16; ++k) {
        int sl = ty * 16 + k;
        dst[(size_t)(sbase + sl) * C_ + cbase + tx] = tile[tx][sl];
    }
}

// ---------- Kernel 2: RoI max pool from NHWC ----------
// grid.x = N*7  (n, ph);  256 threads = channel index. All loop bounds wave-uniform.
__global__ __launch_bounds__(256) void roipool_nhwc_kernel(
    const float* __restrict__ t, const float* __restrict__ rois,
    float* __restrict__ out)
{
    int blk = blockIdx.x;
    int ph = blk % POOLED;
    int n  = blk / POOLED;
    int c  = threadIdx.x;

    const float* r = rois + n * 5;
    int b  = (int)r[0];
    int x1 = (int)(r[1] * SCALE);
    int y1 = (int)(r[2] * SCALE);
    int x2 = (int)(r[3] * SCALE);
    int y2 = (int)(r[4] * SCALE);
    int rh = y2 - y1 + 1;
    int rw = x2 - x1 + 1;

    int hs = y1 + (ph * rh) / POOLED;
    int he = y1 + ((ph + 1) * rh + POOLED - 1) / POOLED;

    int wsr[POOLED], wer[POOLED];
    #pragma unroll
    for (int pw = 0; pw < POOLED; ++pw) {
        wsr[pw] = x1 + (pw * rw) / POOLED;
        wer[pw] = x1 + ((pw + 1) * rw + POOLED - 1) / POOLED;
    }

    float acc[POOLED];
    #pragma unroll
    for (int pw = 0; pw < POOLED; ++pw) acc[pw] = -INFINITY;

    const float* bb = t + (size_t)b * S_ * C_ + c;
    for (int h = hs; h < he; ++h) {
        const float* hp = bb + (size_t)(h * W_) * C_;
        #pragma unroll
        for (int pw = 0; pw < POOLED; ++pw) {
            for (int w = wsr[pw]; w < wer[pw]; ++w) {
                acc[pw] = fmaxf(acc[pw], hp[(size_t)w * C_]);
            }
        }
    }

    float* op = out + (((size_t)n * C_ + c) * POOLED + ph) * POOLED;
    #pragma unroll
    for (int pw = 0; pw < POOLED; ++pw) op[pw] = acc[pw];
}

// ---------- Fallback (round-1 kernel) if workspace too small ----------
__global__ __launch_bounds__(256) void roipool_direct_kernel(
    const float* __restrict__ feat, const float* __restrict__ rois,
    float* __restrict__ out, int total)
{
    int idx = blockIdx.x * blockDim.x + threadIdx.x;
    if (idx >= total) return;
    int pw = idx % POOLED;
    int ph = (idx / POOLED) % POOLED;
    int c  = (idx / (POOLED * POOLED)) % C_;
    int n  = idx / (POOLED * POOLED * C_);
    const float* r = rois + n * 5;
    int b  = (int)r[0];
    int x1 = (int)(r[1] * SCALE);
    int y1 = (int)(r[2] * SCALE);
    int x2 = (int)(r[3] * SCALE);
    int y2 = (int)(r[4] * SCALE);
    int rh = y2 - y1 + 1;
    int rw = x2 - x1 + 1;
    int hs = y1 + (ph * rh) / POOLED;
    int he = y1 + ((ph + 1) * rh + POOLED - 1) / POOLED;
    int ws = x1 + (pw * rw) / POOLED;
    int we = x1 + ((pw + 1) * rw + POOLED - 1) / POOLED;
    const float* plane = feat + ((size_t)b * C_ + c) * (size_t)S_;
    float m = -INFINITY;
    for (int h = hs; h < he; ++h) {
        const float* row = plane + h * W_;
        for (int w = ws; w < we; ++w) m = fmaxf(m, row[w]);
    }
    out[idx] = m;
}

extern "C" void kernel_launch(void* const* d_in, const int* in_sizes, int n_in,
                              void* d_out, int out_size, void* d_ws, size_t ws_size,
                              hipStream_t stream) {
    const float* feat = (const float*)d_in[0];
    const float* rois = (const float*)d_in[1];
    float* out = (float*)d_out;

    int N = in_sizes[1] / 5;
    size_t need = (size_t)4 * S_ * C_ * sizeof(float);  // 12.85 MB

    if (ws_size >= need) {
        float* t = (float*)d_ws;
        dim3 tgrid(S_ / 64, C_ / 64, 4);
        transpose_kernel<<<tgrid, 256, 0, stream>>>(feat, t);
        roipool_nhwc_kernel<<<N * POOLED, 256, 0, stream>>>(t, rois, out);
    } else {
        int total = N * C_ * POOLED * POOLED;
        roipool_direct_kernel<<<(total + 255) / 256, 256, 0, stream>>>(feat, rois, out, total);
    }
}

// Round 3
// 52.521 us; speedup vs baseline: 2.3424x; 2.3424x over previous
//
#include <hip/hip_runtime.h>
#include <math.h>

#define POOLED 7
#define SCALE 0.0625f
#define C_ 256
#define H_ 56
#define W_ 56
#define S_ (H_ * W_)   // 3136

// ---------- Kernel 1: NCHW -> NHWC transpose, float4 both sides ----------
// grid = (S/64, C/64, B), 256 threads. 64x64 tile.
__global__ __launch_bounds__(256) void transpose_kernel(
    const float* __restrict__ src, float* __restrict__ dst)
{
    __shared__ float tile[64][65];
    int b = blockIdx.z;
    int sbase = blockIdx.x * 64;
    int cbase = blockIdx.y * 64;
    int tid = threadIdx.x;

    const float* s0 = src + (size_t)b * C_ * S_;
    float* d0 = dst + (size_t)b * S_ * C_;

    int si = tid & 15;        // s-quad (4 floats each)
    int ci = tid >> 4;        // 0..15
    #pragma unroll
    for (int p = 0; p < 4; ++p) {
        int c = ci + 16 * p;
        float4 v = *(const float4*)(s0 + (size_t)(cbase + c) * S_ + sbase + 4 * si);
        tile[4 * si + 0][c] = v.x;
        tile[4 * si + 1][c] = v.y;
        tile[4 * si + 2][c] = v.z;
        tile[4 * si + 3][c] = v.w;
    }
    __syncthreads();
    int cj = tid & 15;        // c-quad
    int sj = tid >> 4;        // 0..15
    #pragma unroll
    for (int p = 0; p < 4; ++p) {
        int s = sj + 16 * p;
        float4 v;
        v.x = tile[s][4 * cj + 0];
        v.y = tile[s][4 * cj + 1];
        v.z = tile[s][4 * cj + 2];
        v.w = tile[s][4 * cj + 3];
        *(float4*)(d0 + (size_t)(sbase + s) * C_ + cbase + 4 * cj) = v;
    }
}

// ---------- Kernel 2: RoI max pool, one wave per (n, ph, pw) cell ----------
// lane = channel-quad (64 lanes x float4 = 256 channels). Wave-uniform loops.
__global__ __launch_bounds__(256) void roipool_cell_kernel(
    const float* __restrict__ t, const float* __restrict__ rois,
    float* __restrict__ out)
{
    int wid  = (blockIdx.x * 256 + threadIdx.x) >> 6;   // global wave id = cell id
    int lane = threadIdx.x & 63;

    int cell = wid % 49;
    int n    = wid / 49;
    int ph = cell / POOLED;
    int pw = cell % POOLED;

    const float* r = rois + n * 5;
    int b  = (int)r[0];
    int x1 = (int)(r[1] * SCALE);
    int y1 = (int)(r[2] * SCALE);
    int x2 = (int)(r[3] * SCALE);
    int y2 = (int)(r[4] * SCALE);
    int rh = y2 - y1 + 1;
    int rw = x2 - x1 + 1;

    int hs = y1 + (ph * rh) / POOLED;
    int he = y1 + ((ph + 1) * rh + POOLED - 1) / POOLED;
    int ws = x1 + (pw * rw) / POOLED;
    int we = x1 + ((pw + 1) * rw + POOLED - 1) / POOLED;
    // valid indices stay within [0, H-1]/[0, W-1]; no clamping needed (he<=y2+1<=H)

    float4 acc = make_float4(-INFINITY, -INFINITY, -INFINITY, -INFINITY);
    const float4* base = (const float4*)(t + (size_t)b * S_ * C_) + lane;  // float4 units

    for (int h = hs; h < he; ++h) {
        const float4* hp = base + (size_t)(h * W_) * 64;
        int w = ws;
        for (; w + 1 < we; w += 2) {
            float4 v0 = hp[(size_t)w * 64];
            float4 v1 = hp[(size_t)(w + 1) * 64];
            acc.x = fmaxf(acc.x, fmaxf(v0.x, v1.x));
            acc.y = fmaxf(acc.y, fmaxf(v0.y, v1.y));
            acc.z = fmaxf(acc.z, fmaxf(v0.z, v1.z));
            acc.w = fmaxf(acc.w, fmaxf(v0.w, v1.w));
        }
        if (w < we) {
            float4 v0 = hp[(size_t)w * 64];
            acc.x = fmaxf(acc.x, v0.x);
            acc.y = fmaxf(acc.y, v0.y);
            acc.z = fmaxf(acc.z, v0.z);
            acc.w = fmaxf(acc.w, v0.w);
        }
    }

    // out[((n*256 + c)*7 + ph)*7 + pw], c = 4*lane .. 4*lane+3
    float* op = out + ((size_t)n * C_ + 4 * lane) * 49 + ph * POOLED + pw;
    op[0]   = acc.x;
    op[49]  = acc.y;
    op[98]  = acc.z;
    op[147] = acc.w;
}

// ---------- Fallback (round-1 kernel) if workspace too small ----------
__global__ __launch_bounds__(256) void roipool_direct_kernel(
    const float* __restrict__ feat, const float* __restrict__ rois,
    float* __restrict__ out, int total)
{
    int idx = blockIdx.x * blockDim.x + threadIdx.x;
    if (idx >= total) return;
    int pw = idx % POOLED;
    int ph = (idx / POOLED) % POOLED;
    int c  = (idx / (POOLED * POOLED)) % C_;
    int n  = idx / (POOLED * POOLED * C_);
    const float* r = rois + n * 5;
    int b  = (int)r[0];
    int x1 = (int)(r[1] * SCALE);
    int y1 = (int)(r[2] * SCALE);
    int x2 = (int)(r[3] * SCALE);
    int y2 = (int)(r[4] * SCALE);
    int rh = y2 - y1 + 1;
    int rw = x2 - x1 + 1;
    int hs = y1 + (ph * rh) / POOLED;
    int he = y1 + ((ph + 1) * rh + POOLED - 1) / POOLED;
    int ws = x1 + (pw * rw) / POOLED;
    int we = x1 + ((pw + 1) * rw + POOLED - 1) / POOLED;
    const float* plane = feat + ((size_t)b * C_ + c) * (size_t)S_;
    float m = -INFINITY;
    for (int h = hs; h < he; ++h) {
        const float* row = plane + h * W_;
        for (int w = ws; w < we; ++w) m = fmaxf(m, row[w]);
    }
    out[idx] = m;
}

extern "C" void kernel_launch(void* const* d_in, const int* in_sizes, int n_in,
                              void* d_out, int out_size, void* d_ws, size_t ws_size,
                              hipStream_t stream) {
    const float* feat = (const float*)d_in[0];
    const float* rois = (const float*)d_in[1];
    float* out = (float*)d_out;

    int N = in_sizes[1] / 5;
    size_t need = (size_t)4 * S_ * C_ * sizeof(float);  // 12.85 MB

    if (ws_size >= need) {
        float* t = (float*)d_ws;
        dim3 tgrid(S_ / 64, C_ / 64, 4);
        transpose_kernel<<<tgrid, 256, 0, stream>>>(feat, t);
        int cells = N * 49;                 // one wave per cell
        int blocks = (cells + 3) / 4;       // 4 waves per block
        roipool_cell_kernel<<<blocks, 256, 0, stream>>>(t, rois, out);
    } else {
        int total = N * C_ * POOLED * POOLED;
        roipool_direct_kernel<<<(total + 255) / 256, 256, 0, stream>>>(feat, rois, out, total);
    }
}

// Round 4
// 41.495 us; speedup vs baseline: 2.9649x; 1.2657x over previous
//
#include <hip/hip_runtime.h>
#include <math.h>

#define POOLED 7
#define SCALE 0.0625f
#define C_ 256
#define H_ 56
#define W_ 56
#define S_ (H_ * W_)   // 3136
#define NCELL 49

__device__ __forceinline__ float2 fmax2(float2 a, float2 b) {
    return make_float2(fmaxf(a.x, b.x), fmaxf(a.y, b.y));
}

// ---------- Kernel 1: NCHW -> NHWC transpose, 1024 threads, 64x64 tile ----------
// grid = (S/64, C/64, B)
__global__ __launch_bounds__(1024) void nhwc_kernel(
    const float* __restrict__ src, float* __restrict__ dst)
{
    __shared__ float tile[64][65];
    int b = blockIdx.z;
    int sbase = blockIdx.x * 64;
    int cbase = blockIdx.y * 64;
    int tid = threadIdx.x;

    const float* s0 = src + (size_t)b * C_ * S_;
    float* d0 = dst + (size_t)b * S_ * C_;

    {
        int si = tid & 15;         // s-quad
        int c  = tid >> 4;         // 0..63
        float4 v = *(const float4*)(s0 + (size_t)(cbase + c) * S_ + sbase + 4 * si);
        tile[4 * si + 0][c] = v.x;
        tile[4 * si + 1][c] = v.y;
        tile[4 * si + 2][c] = v.z;
        tile[4 * si + 3][c] = v.w;
    }
    __syncthreads();
    {
        int cj = tid & 15;         // c-quad
        int s  = tid >> 4;         // 0..63
        float4 v;
        v.x = tile[s][4 * cj + 0];
        v.y = tile[s][4 * cj + 1];
        v.z = tile[s][4 * cj + 2];
        v.w = tile[s][4 * cj + 3];
        *(float4*)(d0 + (size_t)(sbase + s) * C_ + cbase + 4 * cj) = v;
    }
}

// ---------- Kernel 2: pool. wave = (n, cell, c-half); lane = c-pair (float2) ----------
// writes ws2 in (n, cell, c) layout -> fully coalesced 512B stores per wave.
__global__ __launch_bounds__(256) void pool_kernel(
    const float* __restrict__ t, const float* __restrict__ rois,
    float* __restrict__ ws2, int nwave)
{
    int wid  = blockIdx.x * 4 + (threadIdx.x >> 6);
    if (wid >= nwave) return;
    int lane = threadIdx.x & 63;

    int chalf = wid & 1;
    int cg    = wid >> 1;
    int n     = cg / NCELL;
    int cell  = cg % NCELL;
    int ph = cell / POOLED;
    int pw = cell % POOLED;

    const float* r = rois + n * 5;
    int b  = (int)r[0];
    int x1 = (int)(r[1] * SCALE);
    int y1 = (int)(r[2] * SCALE);
    int x2 = (int)(r[3] * SCALE);
    int y2 = (int)(r[4] * SCALE);
    int rh = y2 - y1 + 1;
    int rw = x2 - x1 + 1;

    int hs = y1 + (ph * rh) / POOLED;
    int he = y1 + ((ph + 1) * rh + POOLED - 1) / POOLED;
    int ws = x1 + (pw * rw) / POOLED;
    int we = x1 + ((pw + 1) * rw + POOLED - 1) / POOLED;

    const float* base = t + (size_t)b * S_ * C_ + chalf * 128 + 2 * lane;

    const float2 NEG = make_float2(-INFINITY, -INFINITY);
    float2 a0 = NEG, a1 = NEG, a2 = NEG, a3 = NEG;

    for (int h = hs; h < he; ++h) {
        const float* hp = base + (size_t)(h * W_) * C_;
        int w = ws;
        for (; w + 3 < we; w += 4) {
            a0 = fmax2(a0, *(const float2*)(hp + (size_t)(w + 0) * C_));
            a1 = fmax2(a1, *(const float2*)(hp + (size_t)(w + 1) * C_));
            a2 = fmax2(a2, *(const float2*)(hp + (size_t)(w + 2) * C_));
            a3 = fmax2(a3, *(const float2*)(hp + (size_t)(w + 3) * C_));
        }
        if (w < we)     a0 = fmax2(a0, *(const float2*)(hp + (size_t)(w + 0) * C_));
        if (w + 1 < we) a1 = fmax2(a1, *(const float2*)(hp + (size_t)(w + 1) * C_));
        if (w + 2 < we) a2 = fmax2(a2, *(const float2*)(hp + (size_t)(w + 2) * C_));
    }
    float2 acc = fmax2(fmax2(a0, a1), fmax2(a2, a3));

    *(float2*)(ws2 + ((size_t)(n * NCELL + cell)) * C_ + chalf * 128 + 2 * lane) = acc;
}

// ---------- Kernel 3: per-n output transpose (cell, c) -> (c, cell) ----------
// grid = (N, C/64), 256 threads. LDS tile [64 c][49 cell] padded.
__global__ __launch_bounds__(256) void outt_kernel(
    const float* __restrict__ ws2, float* __restrict__ out)
{
    __shared__ float tile[64][51];
    int n = blockIdx.x;
    int cbase = blockIdx.y * 64;
    int tid = threadIdx.x;

    const float* src = ws2 + (size_t)n * NCELL * C_;
    // load: 49 cells x 64 channels, coalesced reads (c contiguous)
    int cl = tid & 63;
    int cell0 = tid >> 6;
    #pragma unroll
    for (int k = 0; k < 13; ++k) {
        int cell = cell0 + 4 * k;
        if (cell < NCELL) tile[cl][cell] = src[(size_t)cell * C_ + cbase + cl];
    }
    __syncthreads();
    // store: contiguous region out[n*12544 + cbase*49 .. +3136), coalesced
    float* dst = out + (size_t)n * C_ * NCELL + (size_t)cbase * NCELL;
    #pragma unroll
    for (int k = 0; k < 13; ++k) {
        int f = tid + 256 * k;
        if (f < 64 * NCELL) {
            int c = f / NCELL, cell = f % NCELL;
            dst[f] = tile[c][cell];
        }
    }
}

// ---------- Fallback if workspace too small ----------
__global__ __launch_bounds__(256) void roipool_direct_kernel(
    const float* __restrict__ feat, const float* __restrict__ rois,
    float* __restrict__ out, int total)
{
    int idx = blockIdx.x * blockDim.x + threadIdx.x;
    if (idx >= total) return;
    int pw = idx % POOLED;
    int ph = (idx / POOLED) % POOLED;
    int c  = (idx / (POOLED * POOLED)) % C_;
    int n  = idx / (POOLED * POOLED * C_);
    const float* r = rois + n * 5;
    int b  = (int)r[0];
    int x1 = (int)(r[1] * SCALE);
    int y1 = (int)(r[2] * SCALE);
    int x2 = (int)(r[3] * SCALE);
    int y2 = (int)(r[4] * SCALE);
    int rh = y2 - y1 + 1;
    int rw = x2 - x1 + 1;
    int hs = y1 + (ph * rh) / POOLED;
    int he = y1 + ((ph + 1) * rh + POOLED - 1) / POOLED;
    int ws = x1 + (pw * rw) / POOLED;
    int we = x1 + ((pw + 1) * rw + POOLED - 1) / POOLED;
    const float* plane = feat + ((size_t)b * C_ + c) * (size_t)S_;
    float m = -INFINITY;
    for (int h = hs; h < he; ++h) {
        const float* row = plane + h * W_;
        for (int w = ws; w < we; ++w) m = fmaxf(m, row[w]);
    }
    out[idx] = m;
}

extern "C" void kernel_launch(void* const* d_in, const int* in_sizes, int n_in,
                              void* d_out, int out_size, void* d_ws, size_t ws_size,
                              hipStream_t stream) {
    const float* feat = (const float*)d_in[0];
    const float* rois = (const float*)d_in[1];
    float* out = (float*)d_out;

    int N = in_sizes[1] / 5;
    size_t featElems = (size_t)4 * S_ * C_;
    size_t need = (featElems + (size_t)N * NCELL * C_) * sizeof(float);

    if (ws_size >= need) {
        float* t   = (float*)d_ws;
        float* ws2 = (float*)d_ws + featElems;

        dim3 tgrid(S_ / 64, C_ / 64, 4);
        nhwc_kernel<<<tgrid, 1024, 0, stream>>>(feat, t);

        int nwave = N * NCELL * 2;
        int blocks = (nwave + 3) / 4;
        pool_kernel<<<blocks, 256, 0, stream>>>(t, rois, ws2, nwave);

        dim3 ogrid(N, C_ / 64);
        outt_kernel<<<ogrid, 256, 0, stream>>>(ws2, out);
    } else {
        int total = N * C_ * POOLED * POOLED;
        roipool_direct_kernel<<<(total + 255) / 256, 256, 0, stream>>>(feat, rois, out, total);
    }
}